// Round 25
// baseline (246.644 us; speedup 1.0000x reference)
//
#include <hip/hip_runtime.h>
#include <hip/hip_cooperative_groups.h>
#include <hip/hip_bf16.h>
#include <math.h>

namespace cg = cooperative_groups;

#define HEADS 8
#define DH 32
#define DIM 256
#define INNER 256
#define B_ 2
#define S_ 8
#define H_ 32
#define W_ 16
#define NTOK (B_*S_*H_*W_)   /* 8192 */

#define VHSTRIDE (512*32*16)
#define AOP 264              /* ao_lds pitch (f16) */

typedef _Float16 h16;
typedef h16 half8 __attribute__((ext_vector_type(8)));
typedef h16 half4 __attribute__((ext_vector_type(4)));
typedef float f32x4 __attribute__((ext_vector_type(4)));
typedef unsigned long long u64;

#define QSCALE 0.17677669529663687f

#define GBM 128
#define GBN 64
#define GBK 32
#define GPITCH 40

__device__ __forceinline__ uint4 cvt8(const float4 a, const float4 b) {
    union { h16 h[8]; uint4 u; } p;
    p.h[0] = (h16)a.x; p.h[1] = (h16)a.y; p.h[2] = (h16)a.z; p.h[3] = (h16)a.w;
    p.h[4] = (h16)b.x; p.h[5] = (h16)b.y; p.h[6] = (h16)b.z; p.h[7] = (h16)b.w;
    return p.u;
}

// ---------------------------------------------------------------------------
// Shared epilogue: nt stores (R22-validated). OUT_MODE 3 / 4.
// ---------------------------------------------------------------------------
template <int OUT_MODE>
__device__ __forceinline__ void gemm_epilogue(
    f32x4 (&acc)[4][2], void* __restrict__ outv, int m0, int j0, float oscale,
    int wr, int wc, int r, int g)
{
    #pragma unroll
    for (int fr = 0; fr < 4; ++fr) {
        #pragma unroll
        for (int fc = 0; fc < 2; ++fc) {
            const int col = j0 + wc * 32 + fc * 16 + r;
            if constexpr (OUT_MODE == 4) {
                const int hd = col >> 5, d = col & 31;
                const int rowb = m0 + wr * 64 + fr * 16 + g * 4;
                union { h16 h[4]; u64 u; } p;
                #pragma unroll
                for (int i = 0; i < 4; ++i) p.h[i] = (h16)(acc[fr][fc][i] * oscale);
                h16* dst = (h16*)outv + ((size_t)hd * 512 + (rowb >> 4)) * 512
                           + d * 16 + (rowb & 15);
                __builtin_nontemporal_store(p.u, (u64*)dst);
            } else {
                const int hd = col >> 5, d = col & 31;
                #pragma unroll
                for (int i = 0; i < 4; ++i) {
                    const int row = m0 + wr * 64 + fr * 16 + g * 4 + i;
                    union { h16 hh; unsigned short us; } cv;
                    cv.hh = (h16)(acc[fr][fc][i] * oscale);
                    __builtin_nontemporal_store(cv.us,
                        (unsigned short*)((h16*)outv + ((size_t)hd * NTOK + row) * DH + d));
                }
            }
        }
    }
}

// ---------------------------------------------------------------------------
// SINGLE-buffered GEMM (for fused phase 1 — LDS budget 30720B/block).
// tid = 256-thread sub-unit id. 2 barriers per K-step (block-wide).
// ---------------------------------------------------------------------------
template <int OUT_MODE>
__device__ __forceinline__ void mfma_gemm_sbuf(
    const float* __restrict__ A, const float* __restrict__ W,
    void* __restrict__ outv, int m0, int j0, float oscale, int tid,
    h16* aT, h16* bT)
{
    const int lane = tid & 63;
    const int wid  = tid >> 6;
    const int wr   = wid >> 1;
    const int wc   = wid & 1;
    const int r    = lane & 15;
    const int g    = lane >> 4;

    f32x4 acc[4][2];
    #pragma unroll
    for (int i = 0; i < 4; ++i)
        #pragma unroll
        for (int j = 0; j < 2; ++j)
            acc[i][j] = (f32x4){0.f, 0.f, 0.f, 0.f};

    const int arow  = tid >> 1;
    const int ahalf = (tid & 1) * 16;
    const int brow  = (tid & 127) >> 1;
    const bool doB  = tid < 128;

    for (int k0 = 0; k0 < DIM; k0 += GBK) {
        {
            const float* src = A + (size_t)(m0 + arow) * DIM + k0 + ahalf;
            const float4 u0 = *(const float4*)(src + 0);
            const float4 u1 = *(const float4*)(src + 4);
            const float4 u2 = *(const float4*)(src + 8);
            const float4 u3 = *(const float4*)(src + 12);
            *(uint4*)(aT + arow * GPITCH + ahalf + 0) = cvt8(u0, u1);
            *(uint4*)(aT + arow * GPITCH + ahalf + 8) = cvt8(u2, u3);
        }
        if (doB) {
            const float* src = W + (size_t)(j0 + brow) * DIM + k0 + ahalf;
            const float4 u0 = *(const float4*)(src + 0);
            const float4 u1 = *(const float4*)(src + 4);
            const float4 u2 = *(const float4*)(src + 8);
            const float4 u3 = *(const float4*)(src + 12);
            *(uint4*)(bT + brow * GPITCH + ahalf + 0) = cvt8(u0, u1);
            *(uint4*)(bT + brow * GPITCH + ahalf + 8) = cvt8(u2, u3);
        }
        __syncthreads();

        half8 af[4], bf[2];
        #pragma unroll
        for (int fr = 0; fr < 4; ++fr)
            af[fr] = *(const half8*)(aT + (wr * 64 + fr * 16 + r) * GPITCH + g * 8);
        #pragma unroll
        for (int fc = 0; fc < 2; ++fc)
            bf[fc] = *(const half8*)(bT + (wc * 32 + fc * 16 + r) * GPITCH + g * 8);

        #pragma unroll
        for (int fr = 0; fr < 4; ++fr)
            #pragma unroll
            for (int fc = 0; fc < 2; ++fc)
                acc[fr][fc] = __builtin_amdgcn_mfma_f32_16x16x32_f16(
                    af[fr], bf[fc], acc[fr][fc], 0, 0, 0);
        __syncthreads();
    }

    gemm_epilogue<OUT_MODE>(acc, outv, m0, j0, oscale, wr, wc, r, g);
}

// ---------------------------------------------------------------------------
// DOUBLE-buffered GEMM (R20/R22-validated) — fallback proj kernel.
// ---------------------------------------------------------------------------
template <int OUT_MODE>
__device__ __forceinline__ void mfma_gemm_dbuf(
    const float* __restrict__ A, const float* __restrict__ W,
    void* __restrict__ outv, int m0, int j0, float oscale,
    h16 (*aT)[GBM * GPITCH], h16 (*bT)[GBN * GPITCH])
{
    const int tid  = threadIdx.x;
    const int lane = tid & 63;
    const int wid  = tid >> 6;
    const int wr   = wid >> 1;
    const int wc   = wid & 1;
    const int r    = lane & 15;
    const int g    = lane >> 4;

    f32x4 acc[4][2];
    #pragma unroll
    for (int i = 0; i < 4; ++i)
        #pragma unroll
        for (int j = 0; j < 2; ++j)
            acc[i][j] = (f32x4){0.f, 0.f, 0.f, 0.f};

    const int arow  = tid >> 1;
    const int ahalf = (tid & 1) * 16;
    const int brow  = (tid & 127) >> 1;
    const bool doB  = tid < 128;

    const float* srcA = A + (size_t)(m0 + arow) * DIM + ahalf;
    const float* srcB = W + (size_t)(j0 + brow) * DIM + ahalf;

    float4 ra0, ra1, ra2, ra3, rb0, rb1, rb2, rb3;
    ra0 = *(const float4*)(srcA + 0);  ra1 = *(const float4*)(srcA + 4);
    ra2 = *(const float4*)(srcA + 8);  ra3 = *(const float4*)(srcA + 12);
    if (doB) {
        rb0 = *(const float4*)(srcB + 0);  rb1 = *(const float4*)(srcB + 4);
        rb2 = *(const float4*)(srcB + 8);  rb3 = *(const float4*)(srcB + 12);
    }

    #pragma unroll
    for (int p = 0; p < 8; ++p) {
        h16* a = aT[p & 1];
        h16* b = bT[p & 1];
        *(uint4*)(a + arow * GPITCH + ahalf + 0) = cvt8(ra0, ra1);
        *(uint4*)(a + arow * GPITCH + ahalf + 8) = cvt8(ra2, ra3);
        if (doB) {
            *(uint4*)(b + brow * GPITCH + ahalf + 0) = cvt8(rb0, rb1);
            *(uint4*)(b + brow * GPITCH + ahalf + 8) = cvt8(rb2, rb3);
        }
        __syncthreads();

        if (p < 7) {
            const int k1 = (p + 1) * GBK;
            ra0 = *(const float4*)(srcA + k1 + 0);
            ra1 = *(const float4*)(srcA + k1 + 4);
            ra2 = *(const float4*)(srcA + k1 + 8);
            ra3 = *(const float4*)(srcA + k1 + 12);
            if (doB) {
                rb0 = *(const float4*)(srcB + k1 + 0);
                rb1 = *(const float4*)(srcB + k1 + 4);
                rb2 = *(const float4*)(srcB + k1 + 8);
                rb3 = *(const float4*)(srcB + k1 + 12);
            }
        }

        half8 af[4], bf[2];
        #pragma unroll
        for (int fr = 0; fr < 4; ++fr)
            af[fr] = *(const half8*)(a + (wr * 64 + fr * 16 + r) * GPITCH + g * 8);
        #pragma unroll
        for (int fc = 0; fc < 2; ++fc)
            bf[fc] = *(const half8*)(b + (wc * 32 + fc * 16 + r) * GPITCH + g * 8);

        #pragma unroll
        for (int fr = 0; fr < 4; ++fr)
            #pragma unroll
            for (int fc = 0; fc < 2; ++fc)
                acc[fr][fc] = __builtin_amdgcn_mfma_f32_16x16x32_f16(
                    af[fr], bf[fc], acc[fr][fc], 0, 0, 0);
    }

    gemm_epilogue<OUT_MODE>(acc, outv, m0, j0, oscale, wr, wc, r, g);
}

// ---------------------------------------------------------------------------
// Attention + fused output projection body (R22-validated), shared between
// the cooperative fused kernel (phase 2) and the fallback attn kernel.
// blk in [0,512); tid in [0,512).
// ---------------------------------------------------------------------------
__device__ __forceinline__ void attn_body(
    const h16* __restrict__ qk, const h16* __restrict__ vtb,
    const h16* __restrict__ wof16, const float* __restrict__ bo,
    float* __restrict__ out, const int blk, const int tid,
    h16 (*ao_lds)[AOP])
{
    const int lane = tid & 63;
    const int wid  = __builtin_amdgcn_readfirstlane(tid >> 6);   // 0..7 = head
    const int r    = ((blk & 7) << 6) | (blk >> 3);   // XCD swizzle
    const int head = wid;
    const int h = r & 31, s = (r >> 5) & 7, b = r >> 8;
    const int n_base = r * 16;
    const int c = lane & 15, g = lane >> 4;

    const h16* qb = qk + (size_t)head * NTOK * DH;
    const h16* kb = qk + (size_t)(HEADS + head) * NTOK * DH;
    const h16* vb = vtb + (size_t)head * VHSTRIDE;

    int   tokb[16];
    float kill[16];
    #pragma unroll
    for (int t = 0; t < 16; ++t) {
        const int ds = t / 5, hh = t - 5 * ds;
        const int s2 = s + ds - 1;
        const int h2 = h + hh - 2;
        const bool inb = (t < 15) && ((unsigned)s2 < 8u) && ((unsigned)h2 < 32u);
        const int s2c = min(max(s2, 0), 7);
        const int h2c = min(max(h2, 0), 31);
        tokb[t] = ((b * 8 + s2c) * 32 + h2c) * 16;
        kill[t] = inb ? __builtin_inff() : -1e30f;
    }

    const half8 qf = *(const half8*)(qb + (size_t)(n_base + c) * DH + g * 8);

    f32x4 dots[16];
    #pragma unroll
    for (int t = 0; t < 16; ++t) {
        const half8 kf = *(const half8*)(kb + (size_t)(tokb[t] + c) * DH + g * 8);
        dots[t] = __builtin_amdgcn_mfma_f32_16x16x32_f16(
            kf, qf, (f32x4){0.f, 0.f, 0.f, 0.f}, 0, 0, 0);
    }

    union u2h4 { uint2 u2; half4 hv; } vpre[16];
    #pragma unroll
    for (int t = 0; t < 16; ++t) {
        const int bv = tokb[t] >> 4;
        vpre[t].u2 = *(const uint2*)(vb + (size_t)bv * 512 + c * 16 + 4 * g);
    }

    bool okw[4];
    #pragma unroll
    for (int i = 0; i < 4; ++i) {
        const int w2 = 4 * g + i;
        okw[i] = ((unsigned)(w2 - c + 2) <= 4u);
    }
    float mx = -1e30f;
    #pragma unroll
    for (int t = 0; t < 16; ++t) {
        const float kl = kill[t];
        #pragma unroll
        for (int i = 0; i < 4; ++i) {
            float dv = okw[i] ? dots[t][i] : -1e30f;
            dv = fminf(dv, kl);
            dots[t][i] = dv;
            mx = fmaxf(mx, dv);
        }
    }
    mx = fmaxf(mx, __shfl_xor(mx, 16));
    mx = fmaxf(mx, __shfl_xor(mx, 32));

    float sum = 0.f;
    int d0[16], d1[16];
    #pragma unroll
    for (int t = 0; t < 16; ++t) {
        const float e0v = __expf(dots[t][0] - mx);
        const float e1v = __expf(dots[t][1] - mx);
        const float e2v = __expf(dots[t][2] - mx);
        const float e3v = __expf(dots[t][3] - mx);
        sum += (e0v + e1v) + (e2v + e3v);
        union { h16 hh2[2]; int u; } p0, p1;
        p0.hh2[0] = (h16)e0v; p0.hh2[1] = (h16)e1v;
        p1.hh2[0] = (h16)e2v; p1.hh2[1] = (h16)e3v;
        d0[t] = p0.u; d1[t] = p1.u;
    }
    sum += __shfl_xor(sum, 16);
    sum += __shfl_xor(sum, 32);
    const float inv = 1.f / sum;
    float invq[4];
    #pragma unroll
    for (int i = 0; i < 4; ++i) invq[i] = __shfl(inv, 4 * g + i);

    f32x4 o0 = (f32x4){0.f,0.f,0.f,0.f};
    f32x4 o1 = (f32x4){0.f,0.f,0.f,0.f};
    #pragma unroll
    for (int t = 0; t < 16; ++t) {
        union { int u[2]; half4 hv; } pa;
        pa.u[0] = d0[t]; pa.u[1] = d1[t];

        const int bv = tokb[t] >> 4;
        union u2h4 v1;
        v1.u2 = *(const uint2*)(vb + (size_t)bv * 512 + (c + 16) * 16 + 4 * g);

        o0 = __builtin_amdgcn_mfma_f32_16x16x16f16(pa.hv, vpre[t].hv, o0, 0, 0, 0);
        o1 = __builtin_amdgcn_mfma_f32_16x16x16f16(pa.hv, v1.hv, o1, 0, 0, 0);
    }

    #pragma unroll
    for (int i = 0; i < 4; ++i) {
        ao_lds[4 * g + i][head * DH + c]      = (h16)(o0[i] * invq[i]);
        ao_lds[4 * g + i][head * DH + 16 + c] = (h16)(o1[i] * invq[i]);
    }
    __syncthreads();

    const int n0 = wid * 32;
    f32x4 oacc[2];
    oacc[0] = (f32x4){0.f,0.f,0.f,0.f};
    oacc[1] = (f32x4){0.f,0.f,0.f,0.f};
    #pragma unroll
    for (int kc = 0; kc < 8; ++kc) {
        const half8 af = *(const half8*)&ao_lds[c][kc * 32 + g * 8];
        #pragma unroll
        for (int nt = 0; nt < 2; ++nt) {
            const half8 bf = *(const half8*)(wof16
                + (size_t)(n0 + nt * 16 + c) * DIM + kc * 32 + g * 8);
            oacc[nt] = __builtin_amdgcn_mfma_f32_16x16x32_f16(af, bf, oacc[nt], 0, 0, 0);
        }
    }
    #pragma unroll
    for (int nt = 0; nt < 2; ++nt) {
        const int col = n0 + nt * 16 + c;
        const float badd = bo[col];
        #pragma unroll
        for (int i = 0; i < 4; ++i) {
            const int row = n_base + 4 * g + i;
            __builtin_nontemporal_store(oacc[nt][i] + badd,
                                        out + (size_t)row * INNER + col);
        }
    }
}

// ---------------------------------------------------------------------------
// COOPERATIVE fused kernel. LDS 30720B/block -> 2 blocks/CU under any
// occupancy model -> 512-block cooperative grid admissible (R24 fix).
// ---------------------------------------------------------------------------
__global__ __launch_bounds__(512, 4) void fused_kernel(
    const float* __restrict__ x, const float* __restrict__ q,
    const float* __restrict__ wq, const float* __restrict__ wk,
    const float* __restrict__ wv, const float* __restrict__ wo,
    const float* __restrict__ bo,
    h16* __restrict__ qk, h16* __restrict__ vtb, h16* __restrict__ wof16,
    float* __restrict__ out)
{
    __shared__ h16 aT[2][GBM * GPITCH];   /* 20480 B (per-half single buffer) */
    __shared__ h16 bT[2][GBN * GPITCH];   /* 10240 B */

    cg::grid_group grid = cg::this_grid();

    const int blk  = blockIdx.x;
    const int tid  = threadIdx.x;
    const int half = tid >> 8;
    const int htid = tid & 255;

    // ===== PHASE 1: projections, XCD-partitioned ==========================
    if (blk < 384) {
        const int z   = blk & 7;
        const int k   = (blk >> 3) * 2 + half;   // 0..95 per XCD
        const int mtl = k / 12;
        const int rem = k - mtl * 12;
        const int seg = rem >> 2;
        const int jt  = rem & 3;
        const int mt  = z * 8 + mtl;

        const float* A = (seg == 0) ? q : x;
        const float* W = (seg == 0) ? wq : ((seg == 1) ? wk : wv);

        if (seg == 2) {
            mfma_gemm_sbuf<4>(A, W, vtb, mt * GBM, jt * GBN, 1.0f, htid,
                              aT[half], bT[half]);
        } else {
            h16* outp = qk + (size_t)seg * HEADS * NTOK * DH;
            const float sc = (seg == 0) ? QSCALE : 1.0f;
            mfma_gemm_sbuf<3>(A, W, outp, mt * GBM, jt * GBN, sc, htid,
                              aT[half], bT[half]);
        }
    } else if (blk < 416) {
        const int idx = ((blk - 384) * 512 + tid) * 4;
        const float4 v = *(const float4*)(wo + idx);
        union { h16 h[4]; u64 u; } p;
        p.h[0] = (h16)v.x; p.h[1] = (h16)v.y;
        p.h[2] = (h16)v.z; p.h[3] = (h16)v.w;
        __builtin_nontemporal_store(p.u, (u64*)(wof16 + idx));
    }

    __threadfence();
    grid.sync();   // device barrier; per-XCD L2 stays warm (no kernel boundary)

    // ===== PHASE 2: attention + output projection =========================
    attn_body(qk, vtb, wof16, bo, out, blk, tid,
              reinterpret_cast<h16(*)[AOP]>(&aT[0][0]));
}

// ---------------------------------------------------------------------------
// FALLBACK kernels (R22-validated two-dispatch path).
// ---------------------------------------------------------------------------
__global__ __launch_bounds__(256) void proj_kernel(
    const float* __restrict__ x, const float* __restrict__ q,
    const float* __restrict__ wq, const float* __restrict__ wk,
    const float* __restrict__ wv, const float* __restrict__ wo,
    h16* __restrict__ qk, h16* __restrict__ vtb, h16* __restrict__ wof16)
{
    __shared__ h16 aT[2][GBM * GPITCH];
    __shared__ h16 bT[2][GBN * GPITCH];

    const int seg = blockIdx.y >> 2;
    const int jt  = blockIdx.y & 3;

    if (seg == 3) {
        const int idx = (blockIdx.x * 256 + threadIdx.x) * 4;
        const float4 v = *(const float4*)(wo + idx);
        union { h16 h[4]; u64 u; } p;
        p.h[0] = (h16)v.x; p.h[1] = (h16)v.y;
        p.h[2] = (h16)v.z; p.h[3] = (h16)v.w;
        __builtin_nontemporal_store(p.u, (u64*)(wof16 + idx));
        return;
    }

    const float* A = (seg == 0) ? q : x;
    const float* W = (seg == 0) ? wq : ((seg == 1) ? wk : wv);

    if (seg == 2) {
        mfma_gemm_dbuf<4>(A, W, vtb, blockIdx.x * GBM, jt * GBN, 1.0f, aT, bT);
    } else {
        h16* outp = qk + (size_t)seg * HEADS * NTOK * DH;
        const float sc = (seg == 0) ? QSCALE : 1.0f;
        mfma_gemm_dbuf<3>(A, W, outp, blockIdx.x * GBM, jt * GBN, sc, aT, bT);
    }
}

__global__ __launch_bounds__(512, 4) void attn_kernel(
    const h16* __restrict__ qk, const h16* __restrict__ vtb,
    const h16* __restrict__ wof16, const float* __restrict__ bo,
    float* __restrict__ out)
{
    __shared__ h16 ao_lds[16][AOP];
    attn_body(qk, vtb, wof16, bo, out, blockIdx.x, threadIdx.x, ao_lds);
}

// ---------------------------------------------------------------------------
extern "C" void kernel_launch(void* const* d_in, const int* in_sizes, int n_in,
                              void* d_out, int out_size, void* d_ws, size_t ws_size,
                              hipStream_t stream) {
    const float* x  = (const float*)d_in[0];
    const float* q  = (const float*)d_in[1];
    const float* wq = (const float*)d_in[2];
    const float* wk = (const float*)d_in[3];
    const float* wv = (const float*)d_in[4];
    const float* wo = (const float*)d_in[5];
    const float* bo = (const float*)d_in[6];
    float* out = (float*)d_out;

    h16* qk    = (h16*)d_ws;
    h16* vtb   = qk + (size_t)2 * HEADS * NTOK * DH;
    h16* wof16 = vtb + (size_t)HEADS * VHSTRIDE;

    void* kargs[] = {
        (void*)&x, (void*)&q, (void*)&wq, (void*)&wk, (void*)&wv,
        (void*)&wo, (void*)&bo, (void*)&qk, (void*)&vtb, (void*)&wof16,
        (void*)&out
    };
    hipError_t err = hipLaunchCooperativeKernel((const void*)fused_kernel,
                                                dim3(512), dim3(512), kargs,
                                                0, stream);
    if (err != hipSuccess) {
        // fallback: R22-validated two-kernel path (identical outputs)
        dim3 g1(NTOK / GBM, 13);
        proj_kernel<<<g1, 256, 0, stream>>>(x, q, wq, wk, wv, wo, qk, vtb, wof16);
        attn_kernel<<<512, 512, 0, stream>>>(qk, vtb, wof16, bo, out);
    }
}

// Round 26
// 38.467 us; speedup vs baseline: 6.4119x; 6.4119x over previous
//
#include <hip/hip_runtime.h>
#include <hip/hip_bf16.h>
#include <math.h>

#define HEADS 8
#define DH 32
#define DIM 256
#define INNER 256
#define B_ 2
#define S_ 8
#define H_ 32
#define W_ 16
#define NTOK (B_*S_*H_*W_)   /* 8192 */

// blocked V: vTb[head][tokblk(512)][32 d][16 tok] f16 — head stride 262144
#define VHSTRIDE (512*32*16)
#define AOP 264              /* ao_lds pitch (f16) */

typedef _Float16 h16;
typedef h16 half8 __attribute__((ext_vector_type(8)));
typedef h16 half4 __attribute__((ext_vector_type(4)));
typedef float f32x4 __attribute__((ext_vector_type(4)));
typedef unsigned long long u64;

#define QSCALE 0.17677669529663687f   /* 32^-0.5, folded into Q at proj */

#define GBM 128
#define GBN 64
#define GBK 32
#define GPITCH 40

__device__ __forceinline__ uint4 cvt8(const float4 a, const float4 b) {
    union { h16 h[8]; uint4 u; } p;
    p.h[0] = (h16)a.x; p.h[1] = (h16)a.y; p.h[2] = (h16)a.z; p.h[3] = (h16)a.w;
    p.h[4] = (h16)b.x; p.h[5] = (h16)b.y; p.h[6] = (h16)b.z; p.h[7] = (h16)b.w;
    return p.u;
}

// ---------------------------------------------------------------------------
// Double-buffered single-barrier MFMA GEMM (R20-validated), nt stores (R22-
// validated). OUT_MODE: 3=f16 head-major, 4=blocked-V.
// ---------------------------------------------------------------------------
template <int OUT_MODE>
__device__ __forceinline__ void mfma_gemm_dbuf(
    const float* __restrict__ A, const float* __restrict__ W,
    void* __restrict__ outv, int m0, int j0, float oscale,
    h16 (*aT)[GBM * GPITCH], h16 (*bT)[GBN * GPITCH])
{
    const int tid  = threadIdx.x;
    const int lane = tid & 63;
    const int wid  = tid >> 6;
    const int wr   = wid >> 1;
    const int wc   = wid & 1;
    const int r    = lane & 15;
    const int g    = lane >> 4;

    f32x4 acc[4][2];
    #pragma unroll
    for (int i = 0; i < 4; ++i)
        #pragma unroll
        for (int j = 0; j < 2; ++j)
            acc[i][j] = (f32x4){0.f, 0.f, 0.f, 0.f};

    const int arow  = tid >> 1;
    const int ahalf = (tid & 1) * 16;
    const int brow  = (tid & 127) >> 1;
    const bool doB  = tid < 128;

    const float* srcA = A + (size_t)(m0 + arow) * DIM + ahalf;
    const float* srcB = W + (size_t)(j0 + brow) * DIM + ahalf;

    float4 ra0, ra1, ra2, ra3, rb0, rb1, rb2, rb3;
    ra0 = *(const float4*)(srcA + 0);  ra1 = *(const float4*)(srcA + 4);
    ra2 = *(const float4*)(srcA + 8);  ra3 = *(const float4*)(srcA + 12);
    if (doB) {
        rb0 = *(const float4*)(srcB + 0);  rb1 = *(const float4*)(srcB + 4);
        rb2 = *(const float4*)(srcB + 8);  rb3 = *(const float4*)(srcB + 12);
    }

    #pragma unroll
    for (int p = 0; p < 8; ++p) {
        h16* a = aT[p & 1];
        h16* b = bT[p & 1];
        *(uint4*)(a + arow * GPITCH + ahalf + 0) = cvt8(ra0, ra1);
        *(uint4*)(a + arow * GPITCH + ahalf + 8) = cvt8(ra2, ra3);
        if (doB) {
            *(uint4*)(b + brow * GPITCH + ahalf + 0) = cvt8(rb0, rb1);
            *(uint4*)(b + brow * GPITCH + ahalf + 8) = cvt8(rb2, rb3);
        }
        __syncthreads();           // single barrier per K-step (dbuf)

        if (p < 7) {               // next step's loads in flight during MFMA
            const int k1 = (p + 1) * GBK;
            ra0 = *(const float4*)(srcA + k1 + 0);
            ra1 = *(const float4*)(srcA + k1 + 4);
            ra2 = *(const float4*)(srcA + k1 + 8);
            ra3 = *(const float4*)(srcA + k1 + 12);
            if (doB) {
                rb0 = *(const float4*)(srcB + k1 + 0);
                rb1 = *(const float4*)(srcB + k1 + 4);
                rb2 = *(const float4*)(srcB + k1 + 8);
                rb3 = *(const float4*)(srcB + k1 + 12);
            }
        }

        half8 af[4], bf[2];
        #pragma unroll
        for (int fr = 0; fr < 4; ++fr)
            af[fr] = *(const half8*)(a + (wr * 64 + fr * 16 + r) * GPITCH + g * 8);
        #pragma unroll
        for (int fc = 0; fc < 2; ++fc)
            bf[fc] = *(const half8*)(b + (wc * 32 + fc * 16 + r) * GPITCH + g * 8);

        #pragma unroll
        for (int fr = 0; fr < 4; ++fr)
            #pragma unroll
            for (int fc = 0; fc < 2; ++fc)
                acc[fr][fc] = __builtin_amdgcn_mfma_f32_16x16x32_f16(
                    af[fr], bf[fc], acc[fr][fc], 0, 0, 0);
    }

    #pragma unroll
    for (int fr = 0; fr < 4; ++fr) {
        #pragma unroll
        for (int fc = 0; fc < 2; ++fc) {
            const int col = j0 + wc * 32 + fc * 16 + r;
            if constexpr (OUT_MODE == 4) {
                const int hd = col >> 5, d = col & 31;
                const int rowb = m0 + wr * 64 + fr * 16 + g * 4;
                union { h16 h[4]; u64 u; } p;
                #pragma unroll
                for (int i = 0; i < 4; ++i) p.h[i] = (h16)(acc[fr][fc][i] * oscale);
                h16* dst = (h16*)outv + ((size_t)hd * 512 + (rowb >> 4)) * 512
                           + d * 16 + (rowb & 15);
                __builtin_nontemporal_store(p.u, (u64*)dst);
            } else {   // OUT_MODE == 3
                const int hd = col >> 5, d = col & 31;
                #pragma unroll
                for (int i = 0; i < 4; ++i) {
                    const int row = m0 + wr * 64 + fr * 16 + g * 4 + i;
                    union { h16 hh; unsigned short us; } cv;
                    cv.hh = (h16)(acc[fr][fc][i] * oscale);
                    __builtin_nontemporal_store(cv.us,
                        (unsigned short*)((h16*)outv + ((size_t)hd * NTOK + row) * DH + d));
                }
            }
        }
    }
}

// ---------------------------------------------------------------------------
// Kernel 1: projections (dbuf GEMM, nt stores) + wo f32->f16 slice.
// ---------------------------------------------------------------------------
__global__ __launch_bounds__(256) void proj_kernel(
    const float* __restrict__ x, const float* __restrict__ q,
    const float* __restrict__ wq, const float* __restrict__ wk,
    const float* __restrict__ wv, const float* __restrict__ wo,
    h16* __restrict__ qk, h16* __restrict__ vtb, h16* __restrict__ wof16)
{
    __shared__ h16 aT[2][GBM * GPITCH];
    __shared__ h16 bT[2][GBN * GPITCH];

    const int seg = blockIdx.y >> 2;
    const int jt  = blockIdx.y & 3;

    if (seg == 3) {            // wo conversion: 64 blocks x 256 thr x 4 f32
        const int idx = (blockIdx.x * 256 + threadIdx.x) * 4;
        const float4 v = *(const float4*)(wo + idx);
        union { h16 h[4]; u64 u; } p;
        p.h[0] = (h16)v.x; p.h[1] = (h16)v.y;
        p.h[2] = (h16)v.z; p.h[3] = (h16)v.w;
        __builtin_nontemporal_store(p.u, (u64*)(wof16 + idx));
        return;
    }

    const float* A = (seg == 0) ? q : x;
    const float* W = (seg == 0) ? wq : ((seg == 1) ? wk : wv);

    if (seg == 2) {
        mfma_gemm_dbuf<4>(A, W, vtb, blockIdx.x * GBM, jt * GBN, 1.0f, aT, bT);
    } else {
        h16* outp = qk + (size_t)seg * HEADS * NTOK * DH;
        const float sc = (seg == 0) ? QSCALE : 1.0f;
        mfma_gemm_dbuf<3>(A, W, outp, blockIdx.x * GBM, jt * GBN, sc, aT, bT);
    }
}

// ---------------------------------------------------------------------------
// Kernel 2: FUSED attention + output projection (R17 structure; out stores
// non-temporal — host-only consumer, keeps K/V lines resident).
// ---------------------------------------------------------------------------
__global__ __launch_bounds__(512, 4) void attn_kernel(
    const h16* __restrict__ qk, const h16* __restrict__ vtb,
    const h16* __restrict__ wof16, const float* __restrict__ bo,
    float* __restrict__ out)
{
    __shared__ h16 ao_lds[16][AOP];

    const int tid  = threadIdx.x;
    const int lane = tid & 63;
    const int wid  = __builtin_amdgcn_readfirstlane(tid >> 6);   // 0..7 = head
    const int xr   = blockIdx.x;
    const int r    = ((xr & 7) << 6) | (xr >> 3);    // XCD swizzle (512 = 8*64)
    const int head = wid;
    const int h = r & 31, s = (r >> 5) & 7, b = r >> 8;
    const int n_base = r * 16;
    const int c = lane & 15, g = lane >> 4;

    const h16* qb = qk + (size_t)head * NTOK * DH;
    const h16* kb = qk + (size_t)(HEADS + head) * NTOK * DH;
    const h16* vb = vtb + (size_t)head * VHSTRIDE;

    int   tokb[16];
    float kill[16];
    #pragma unroll
    for (int t = 0; t < 16; ++t) {
        const int ds = t / 5, hh = t - 5 * ds;
        const int s2 = s + ds - 1;
        const int h2 = h + hh - 2;
        const bool inb = (t < 15) && ((unsigned)s2 < 8u) && ((unsigned)h2 < 32u);
        const int s2c = min(max(s2, 0), 7);
        const int h2c = min(max(h2, 0), 31);
        tokb[t] = ((b * 8 + s2c) * 32 + h2c) * 16;
        kill[t] = inb ? __builtin_inff() : -1e30f;
    }

    const half8 qf = *(const half8*)(qb + (size_t)(n_base + c) * DH + g * 8);

    f32x4 dots[16];
    #pragma unroll
    for (int t = 0; t < 16; ++t) {
        const half8 kf = *(const half8*)(kb + (size_t)(tokb[t] + c) * DH + g * 8);
        dots[t] = __builtin_amdgcn_mfma_f32_16x16x32_f16(
            kf, qf, (f32x4){0.f, 0.f, 0.f, 0.f}, 0, 0, 0);
    }

    union u2h4 { uint2 u2; half4 hv; } vpre[16];
    #pragma unroll
    for (int t = 0; t < 16; ++t) {
        const int bv = tokb[t] >> 4;
        vpre[t].u2 = *(const uint2*)(vb + (size_t)bv * 512 + c * 16 + 4 * g);
    }

    bool okw[4];
    #pragma unroll
    for (int i = 0; i < 4; ++i) {
        const int w2 = 4 * g + i;
        okw[i] = ((unsigned)(w2 - c + 2) <= 4u);
    }
    float mx = -1e30f;
    #pragma unroll
    for (int t = 0; t < 16; ++t) {
        const float kl = kill[t];
        #pragma unroll
        for (int i = 0; i < 4; ++i) {
            float dv = okw[i] ? dots[t][i] : -1e30f;
            dv = fminf(dv, kl);
            dots[t][i] = dv;
            mx = fmaxf(mx, dv);
        }
    }
    mx = fmaxf(mx, __shfl_xor(mx, 16));
    mx = fmaxf(mx, __shfl_xor(mx, 32));

    float sum = 0.f;
    int d0[16], d1[16];
    #pragma unroll
    for (int t = 0; t < 16; ++t) {
        const float e0v = __expf(dots[t][0] - mx);
        const float e1v = __expf(dots[t][1] - mx);
        const float e2v = __expf(dots[t][2] - mx);
        const float e3v = __expf(dots[t][3] - mx);
        sum += (e0v + e1v) + (e2v + e3v);
        union { h16 hh2[2]; int u; } p0, p1;
        p0.hh2[0] = (h16)e0v; p0.hh2[1] = (h16)e1v;
        p1.hh2[0] = (h16)e2v; p1.hh2[1] = (h16)e3v;
        d0[t] = p0.u; d1[t] = p1.u;
    }
    sum += __shfl_xor(sum, 16);
    sum += __shfl_xor(sum, 32);
    const float inv = 1.f / sum;
    float invq[4];
    #pragma unroll
    for (int i = 0; i < 4; ++i) invq[i] = __shfl(inv, 4 * g + i);

    f32x4 o0 = (f32x4){0.f,0.f,0.f,0.f};
    f32x4 o1 = (f32x4){0.f,0.f,0.f,0.f};
    #pragma unroll
    for (int t = 0; t < 16; ++t) {
        union { int u[2]; half4 hv; } pa;
        pa.u[0] = d0[t]; pa.u[1] = d1[t];

        const int bv = tokb[t] >> 4;
        union u2h4 v1;
        v1.u2 = *(const uint2*)(vb + (size_t)bv * 512 + (c + 16) * 16 + 4 * g);

        o0 = __builtin_amdgcn_mfma_f32_16x16x16f16(pa.hv, vpre[t].hv, o0, 0, 0, 0);
        o1 = __builtin_amdgcn_mfma_f32_16x16x16f16(pa.hv, v1.hv, o1, 0, 0, 0);
    }

    #pragma unroll
    for (int i = 0; i < 4; ++i) {
        ao_lds[4 * g + i][head * DH + c]      = (h16)(o0[i] * invq[i]);
        ao_lds[4 * g + i][head * DH + 16 + c] = (h16)(o1[i] * invq[i]);
    }
    __syncthreads();

    const int n0 = wid * 32;
    f32x4 oacc[2];
    oacc[0] = (f32x4){0.f,0.f,0.f,0.f};
    oacc[1] = (f32x4){0.f,0.f,0.f,0.f};
    #pragma unroll
    for (int kc = 0; kc < 8; ++kc) {
        const half8 af = *(const half8*)&ao_lds[c][kc * 32 + g * 8];
        #pragma unroll
        for (int nt = 0; nt < 2; ++nt) {
            const half8 bf = *(const half8*)(wof16
                + (size_t)(n0 + nt * 16 + c) * DIM + kc * 32 + g * 8);
            oacc[nt] = __builtin_amdgcn_mfma_f32_16x16x32_f16(af, bf, oacc[nt], 0, 0, 0);
        }
    }
    #pragma unroll
    for (int nt = 0; nt < 2; ++nt) {
        const int col = n0 + nt * 16 + c;
        const float badd = bo[col];
        #pragma unroll
        for (int i = 0; i < 4; ++i) {
            const int row = n_base + 4 * g + i;
            __builtin_nontemporal_store(oacc[nt][i] + badd,
                                        out + (size_t)row * INNER + col);
        }
    }
}

// ---------------------------------------------------------------------------
extern "C" void kernel_launch(void* const* d_in, const int* in_sizes, int n_in,
                              void* d_out, int out_size, void* d_ws, size_t ws_size,
                              hipStream_t stream) {
    const float* x  = (const float*)d_in[0];
    const float* q  = (const float*)d_in[1];
    const float* wq = (const float*)d_in[2];
    const float* wk = (const float*)d_in[3];
    const float* wv = (const float*)d_in[4];
    const float* wo = (const float*)d_in[5];
    const float* bo = (const float*)d_in[6];
    float* out = (float*)d_out;

    // ws: qk f16 [2][8][NTOK][32] (8MB) + vtb (4MB) + wof16 (128KB)
    h16* qk    = (h16*)d_ws;
    h16* vtb   = qk + (size_t)2 * HEADS * NTOK * DH;
    h16* wof16 = vtb + (size_t)HEADS * VHSTRIDE;

    dim3 g1(NTOK / GBM, 13);
    proj_kernel<<<g1, 256, 0, stream>>>(x, q, wq, wk, wv, wo, qk, vtb, wof16);

    attn_kernel<<<512, 512, 0, stream>>>(qk, vtb, wof16, bo, out);
}